// Round 1
// baseline (549.812 us; speedup 1.0000x reference)
//
#include <hip/hip_runtime.h>

typedef __attribute__((ext_vector_type(8))) short short8;
typedef __attribute__((ext_vector_type(4))) float floatx4;
typedef unsigned int u32;
typedef unsigned short u16;

// ---------- helpers ----------
__device__ __forceinline__ u16 f2bf(float f) {
  u32 u = __float_as_uint(f);
  u += 0x7FFFu + ((u >> 16) & 1u);   // RNE
  return (u16)(u >> 16);
}

typedef const __attribute__((address_space(1))) u32* gp1_t;
typedef __attribute__((address_space(3))) u32* lp3_t;

__device__ __forceinline__ void gld16(const void* g, void* l) {
  // async global -> LDS, 16B per lane; LDS dest is wave-uniform base + lane*16
  __builtin_amdgcn_global_load_lds((gp1_t)g, (lp3_t)l, 16, 0, 0);
}

// ---------- kernel 1: x fp32 -> bf16 ----------
__global__ __launch_bounds__(256) void xconv(const float* __restrict__ x,
                                             u16* __restrict__ xb, long long n4) {
  long long i = (long long)blockIdx.x * 256 + threadIdx.x;
  if (i >= n4) return;
  float4 v = ((const float4*)x)[i];
  ushort4 o;
  o.x = f2bf(v.x); o.y = f2bf(v.y); o.z = f2bf(v.z); o.w = f2bf(v.w);
  ((ushort4*)xb)[i] = o;
}

// ---------- kernel 2: dequant int4 -> Wt[n][k] bf16 (transposed) ----------
__global__ __launch_bounds__(256) void dequant(
    const int* __restrict__ qw, const int* __restrict__ qz,
    const int* __restrict__ qs, const float* __restrict__ qsz,
    const float* __restrict__ qss, const int* __restrict__ gidx,
    u16* __restrict__ Wt, int IN, int OUT) {
  const int n = blockIdx.x * 64 + (threadIdx.x & 63);
  const int w = threadIdx.x >> 6;            // 0..3
  const int k0 = blockIdx.y * 128 + w * 32;  // one 32-wide group per wave-slice
  const int g = gidx[k0];                    // uniform across wave
  const int kk0 = k0 >> 3;                   // 4 packed rows
  const int zq = ((qz[(size_t)g * (OUT >> 3) + (n >> 3)] >> (4 * (n & 7))) & 15) + 1;
  const float sc = ((float)qs[(size_t)g * OUT + n] - qsz[g]) * qss[g];
  u16* dst = Wt + (size_t)n * IN + k0;
#pragma unroll
  for (int j = 0; j < 4; ++j) {
    const int w32 = qw[(size_t)(kk0 + j) * OUT + n];   // coalesced across lanes
    u16 o[8];
#pragma unroll
    for (int s = 0; s < 8; ++s)
      o[s] = f2bf((float)(((w32 >> (4 * s)) & 15) - zq) * sc);
    uint4 pk;
    pk.x = (u32)o[0] | ((u32)o[1] << 16);
    pk.y = (u32)o[2] | ((u32)o[3] << 16);
    pk.z = (u32)o[4] | ((u32)o[5] << 16);
    pk.w = (u32)o[6] | ((u32)o[7] << 16);
    *(uint4*)(dst + j * 8) = pk;
  }
}

// ---------- kernel 3: 256x256 deep-pipelined bf16 GEMM ----------
// C = A(MxK) * Bt(NxK)^T.  8 waves (2m x 4n), per-wave 128x64 output,
// ring of 4 K-slots (BK=32) in LDS (4*256*32*2B*2ops = 128 KiB).
// Per step (one K-slot): 2 phases of {stage-issue | 8/4 ds_read_b128 |
// s_barrier | 16 MFMA (setprio-wrapped) | s_barrier}, counted
// s_waitcnt vmcnt(8) once per step (never 0 in steady state).
// Race-freedom: stage for slot s+3 (ring (s-1)&3) is issued in step s,
// strictly after step s-1's final barrier (which followed the last reads of
// that ring slot); per-wave vmcnt(8) before the end-of-step barrier
// guarantees slot s+1 landed in LDS for all waves.
// Swizzle: LDS row stride = 32 bf16 = 64B; ds_read_b128 of 16 rows at a
// fixed 16B chunk would be 8-way bank conflicted. Store chunk^= (row>>1)&3
// (applied on the global source col since gld_lds writes linearly), undo on
// the ds_read address -> 8 distinct 16B granules per 8 rows = 2 lanes/bank.
__global__ __launch_bounds__(512, 2) void gemm256(const u16* __restrict__ A,
                                                  const u16* __restrict__ Bt,
                                                  float* __restrict__ C,
                                                  int M, int N, int K) {
  __shared__ u16 As[4][256 * 32];
  __shared__ u16 Bs[4][256 * 32];
  const int tid = threadIdx.x;
  const int lane = tid & 63;
  const int wave = tid >> 6;          // 0..7
  const int wm = wave >> 2;           // 0..1
  const int wn = wave & 3;            // 0..3
  const int lr = lane & 15, quad = lane >> 4;

  // bijective XCD-aware block swizzle (m204 form)
  const int nbx = N >> 8;
  const int nwg = gridDim.x;
  const int bid = blockIdx.x;
  const int q8 = nwg >> 3, r8 = nwg & 7;
  const int xcd = bid & 7, loc = bid >> 3;
  const int swz = (xcd < r8 ? xcd * (q8 + 1) : r8 * (q8 + 1) + (xcd - r8) * q8) + loc;
  const int n0 = (swz % nbx) << 8;
  const int m0 = (swz / nbx) << 8;

  floatx4 acc[8][4] = {};

  // ---- staging source (per-thread global addr carries the swizzle) ----
  // call covers 128 rows (64B each); this thread: row +=(lane>>2), chunk lane&3
  const int schunk = (lane & 3) ^ ((lane >> 3) & 3);  // == (lane&3)^((row>>1)&3)
  const u16* aS = A + (size_t)(m0 + wave * 16 + (lane >> 2)) * K + schunk * 8;
  const u16* bS = Bt + (size_t)(n0 + wave * 16 + (lane >> 2)) * K + schunk * 8;
  const size_t cstep = (size_t)128 * K;  // second 128-row call

  // ---- fragment read base (per-lane, swizzle undone) ----
  const int rx = (quad ^ ((lr >> 1) & 3)) * 8;
  const int abase = (wm * 128 + lr) * 32 + rx;  // + qm*2048 + mt*512
  const int bbase = (wn * 64 + lr) * 32 + rx;   // + nt*512

  const int NS = K >> 5;  // K-slots of 32

  // ---- prologue: stage slots 0..2, wait until slot 0 landed ----
  for (int s = 0; s < 3; ++s) {
    const u16* ga = aS + (size_t)s * 32;
    const u16* gb = bS + (size_t)s * 32;
    gld16(ga, &As[s][wave * 512]);
    gld16(ga + cstep, &As[s][wave * 512 + 4096]);
    gld16(gb, &Bs[s][wave * 512]);
    gld16(gb + cstep, &Bs[s][wave * 512 + 4096]);
  }
  asm volatile("s_waitcnt vmcnt(8)" ::: "memory");
  __builtin_amdgcn_s_barrier();

#define GSTEP(sv, DO_STAGE, VMW)                                               \
  do {                                                                         \
    const int ring_ = (sv) & 3;                                                \
    const u16* pa_ = &As[ring_][abase];                                        \
    const u16* pb_ = &Bs[ring_][bbase];                                        \
    /* phase A: stage A(slot s+3) | read A(qm=0)+B | bar | 16 MFMA | bar */    \
    if (DO_STAGE) {                                                            \
      const int r2_ = ((sv) + 3) & 3;                                          \
      const u16* ga_ = aS + (size_t)((sv) + 3) * 32;                           \
      gld16(ga_, &As[r2_][wave * 512]);                                        \
      gld16(ga_ + cstep, &As[r2_][wave * 512 + 4096]);                         \
    }                                                                          \
    short8 aF[4], bF[4];                                                       \
    _Pragma("unroll") for (int t = 0; t < 4; ++t)                              \
        aF[t] = *(const short8*)(pa_ + t * 512);                               \
    _Pragma("unroll") for (int t = 0; t < 4; ++t)                              \
        bF[t] = *(const short8*)(pb_ + t * 512);                               \
    __builtin_amdgcn_s_barrier();                                              \
    __builtin_amdgcn_s_setprio(1);                                             \
    _Pragma("unroll") for (int mt = 0; mt < 4; ++mt)                           \
      _Pragma("unroll") for (int nt = 0; nt < 4; ++nt)                         \
        acc[mt][nt] = __builtin_amdgcn_mfma_f32_16x16x32_bf16(                 \
            aF[mt], bF[nt], acc[mt][nt], 0, 0, 0);                             \
    __builtin_amdgcn_s_setprio(0);                                             \
    __builtin_amdgcn_s_barrier();                                              \
    /* phase B: stage B(slot s+3) | read A(qm=1) | 16 MFMA | vmcnt | bar */    \
    if (DO_STAGE) {                                                            \
      const int r2_ = ((sv) + 3) & 3;                                          \
      const u16* gb_ = bS + (size_t)((sv) + 3) * 32;                           \
      gld16(gb_, &Bs[r2_][wave * 512]);                                        \
      gld16(gb_ + cstep, &Bs[r2_][wave * 512 + 4096]);                         \
    }                                                                          \
    _Pragma("unroll") for (int t = 0; t < 4; ++t)                              \
        aF[t] = *(const short8*)(pa_ + 2048 + t * 512);                        \
    __builtin_amdgcn_s_setprio(1);                                             \
    _Pragma("unroll") for (int mt = 0; mt < 4; ++mt)                           \
      _Pragma("unroll") for (int nt = 0; nt < 4; ++nt)                         \
        acc[4 + mt][nt] = __builtin_amdgcn_mfma_f32_16x16x32_bf16(             \
            aF[mt], bF[nt], acc[4 + mt][nt], 0, 0, 0);                         \
    __builtin_amdgcn_s_setprio(0);                                             \
    VMW;                                                                       \
    __builtin_amdgcn_s_barrier();                                              \
  } while (0)

  int s = 0;
  const int NSm3 = NS - 3;
  for (; s < NSm3; ++s)
    GSTEP(s, 1, asm volatile("s_waitcnt vmcnt(8)" ::: "memory"));
  GSTEP(s, 0, asm volatile("s_waitcnt vmcnt(4)" ::: "memory")); ++s;
  GSTEP(s, 0, asm volatile("s_waitcnt vmcnt(0)" ::: "memory")); ++s;
  GSTEP(s, 0, (void)0);
#undef GSTEP

  // ---- epilogue: C/D layout col=lane&15, row=quad*4+reg ----
#pragma unroll
  for (int qm = 0; qm < 2; ++qm)
#pragma unroll
    for (int mt = 0; mt < 4; ++mt)
#pragma unroll
      for (int nt = 0; nt < 4; ++nt)
#pragma unroll
        for (int r = 0; r < 4; ++r) {
          int row = m0 + wm * 128 + qm * 64 + mt * 16 + quad * 4 + r;
          int col = n0 + wn * 64 + nt * 16 + lr;
          C[(size_t)row * N + col] = acc[qm * 4 + mt][nt][r];
        }
}

// ---------- kernel 3b (fallback): 128x128 bf16 GEMM (previous version) ----------
__global__ __launch_bounds__(256) void gemm(const u16* __restrict__ A,
                                            const u16* __restrict__ Bt,
                                            float* __restrict__ C,
                                            int M, int N, int K) {
  __shared__ u16 As[128 * 64];
  __shared__ u16 Bs[128 * 64];
  const int tid = threadIdx.x;
  const int lane = tid & 63;
  const int wave = tid >> 6;
  const int wm = wave & 1, wn = wave >> 1;
  const int lr = lane & 15, quad = lane >> 4;
  const int m0 = blockIdx.y * 128, n0 = blockIdx.x * 128;

  floatx4 acc[4][4] = {};

  const int srowB = (lane >> 3);
  const int schunk = (lane & 7) ^ srowB;
  const int rowA0 = wave * 32;
  const u16* aSrc = A + (size_t)(m0 + rowA0 + srowB) * K + schunk * 8;
  const u16* bSrc = Bt + (size_t)(n0 + rowA0 + srowB) * K + schunk * 8;
  u16* aDst = &As[rowA0 * 64];
  u16* bDst = &Bs[rowA0 * 64];
  const size_t rstep = (size_t)8 * K;

  const int rx = lr & 7;

  for (int k0 = 0; k0 < K; k0 += 64) {
    __syncthreads();
#pragma unroll
    for (int c = 0; c < 4; ++c) {
      gld16(aSrc + c * rstep + k0, aDst + c * 8 * 64);
      gld16(bSrc + c * rstep + k0, bDst + c * 8 * 64);
    }
    __syncthreads();

#pragma unroll
    for (int h = 0; h < 2; ++h) {
      short8 aF[4], bF[4];
      const int rc = ((quad + 4 * h) ^ rx) * 8;
#pragma unroll
      for (int t = 0; t < 4; ++t) {
        aF[t] = *(const short8*)&As[(wm * 64 + t * 16 + lr) * 64 + rc];
        bF[t] = *(const short8*)&Bs[(wn * 64 + t * 16 + lr) * 64 + rc];
      }
#pragma unroll
      for (int mt = 0; mt < 4; ++mt)
#pragma unroll
        for (int nt = 0; nt < 4; ++nt)
          acc[mt][nt] = __builtin_amdgcn_mfma_f32_16x16x32_bf16(
              aF[mt], bF[nt], acc[mt][nt], 0, 0, 0);
    }
  }

#pragma unroll
  for (int mt = 0; mt < 4; ++mt)
#pragma unroll
    for (int nt = 0; nt < 4; ++nt)
#pragma unroll
      for (int r = 0; r < 4; ++r) {
        int row = m0 + wm * 64 + mt * 16 + quad * 4 + r;
        int col = n0 + wn * 64 + nt * 16 + lr;
        C[(size_t)row * N + col] = acc[mt][nt][r];
      }
}

// ---------- fallback: naive dequant-on-the-fly ----------
__global__ void naive(const float* __restrict__ x, const int* __restrict__ qw,
                      const int* __restrict__ qz, const int* __restrict__ qs,
                      const float* __restrict__ qsz, const float* __restrict__ qss,
                      const int* __restrict__ gidx, float* __restrict__ out,
                      int M, int N, int K) {
  int n = blockIdx.x * 64 + (threadIdx.x & 63);
  int m = blockIdx.y * 4 + (threadIdx.x >> 6);
  if (n >= N || m >= M) return;
  float acc = 0.f;
  for (int kk = 0; kk < K / 8; ++kk) {
    int w32 = qw[(size_t)kk * N + n];
#pragma unroll
    for (int s = 0; s < 8; ++s) {
      int k = kk * 8 + s;
      int g = gidx[k];
      int zq = ((qz[(size_t)g * (N >> 3) + (n >> 3)] >> (4 * (n & 7))) & 15) + 1;
      float sc = ((float)qs[(size_t)g * N + n] - qsz[g]) * qss[g];
      acc += x[(size_t)m * K + k] * ((float)((w32 >> (4 * s)) & 15) - (float)zq) * sc;
    }
  }
  out[(size_t)m * N + n] = acc;
}

extern "C" void kernel_launch(void* const* d_in, const int* in_sizes, int n_in,
                              void* d_out, int out_size, void* d_ws, size_t ws_size,
                              hipStream_t stream) {
  const float* x = (const float*)d_in[0];
  const int* qw = (const int*)d_in[1];
  const int* qz = (const int*)d_in[2];
  const int* qs = (const int*)d_in[3];
  const float* qsz = (const float*)d_in[4];
  const float* qss = (const float*)d_in[5];
  const int* gidx = (const int*)d_in[6];
  const int IN = in_sizes[6];                                   // 4096
  const int OUT = (int)(((long long)in_sizes[1] * 8) / IN);     // 4096
  const int M = in_sizes[0] / IN;                               // 8192
  float* out = (float*)d_out;

  size_t bytesW = (size_t)IN * OUT * 2;
  size_t bytesX = (size_t)M * IN * 2;
  bool haveWs = (ws_size >= bytesW + bytesX);
  bool fast256 = haveWs && (M % 256 == 0) && (OUT % 256 == 0) && (IN % 128 == 0);
  bool fast128 = haveWs && (M % 128 == 0) && (OUT % 128 == 0) && (IN % 128 == 0);

  if (fast256 || fast128) {
    u16* Wt = (u16*)d_ws;
    u16* Xb = (u16*)((char*)d_ws + bytesW);
    long long n4 = (long long)M * IN / 4;
    int cb = (int)((n4 + 255) / 256);
    xconv<<<cb, 256, 0, stream>>>(x, Xb, n4);
    dequant<<<dim3(OUT / 64, IN / 128), 256, 0, stream>>>(qw, qz, qs, qsz, qss,
                                                          gidx, Wt, IN, OUT);
    if (fast256) {
      int nblk = (M / 256) * (OUT / 256);
      gemm256<<<dim3(nblk), 512, 0, stream>>>(Xb, Wt, out, M, OUT, IN);
    } else {
      gemm<<<dim3(OUT / 128, M / 128), 256, 0, stream>>>(Xb, Wt, out, M, OUT, IN);
    }
  } else {
    naive<<<dim3((OUT + 63) / 64, (M + 3) / 4), 256, 0, stream>>>(
        x, qw, qz, qs, qsz, qss, gidx, out, M, OUT, IN);
  }
}

// Round 2
// 489.758 us; speedup vs baseline: 1.1226x; 1.1226x over previous
//
#include <hip/hip_runtime.h>

typedef __attribute__((ext_vector_type(8))) short short8;
typedef __attribute__((ext_vector_type(4))) float floatx4;
typedef unsigned int u32;
typedef unsigned short u16;

// ---------- helpers ----------
__device__ __forceinline__ u16 f2bf(float f) {
  u32 u = __float_as_uint(f);
  u += 0x7FFFu + ((u >> 16) & 1u);   // RNE
  return (u16)(u >> 16);
}

typedef const __attribute__((address_space(1))) u32* gp1_t;
typedef __attribute__((address_space(3))) u32* lp3_t;

__device__ __forceinline__ void gld16(const void* g, void* l) {
  // async global -> LDS, 16B per lane; LDS dest is wave-uniform base + lane*16
  __builtin_amdgcn_global_load_lds((gp1_t)g, (lp3_t)l, 16, 0, 0);
}

// ---------- kernel 1: x fp32 -> bf16 ----------
__global__ __launch_bounds__(256) void xconv(const float* __restrict__ x,
                                             u16* __restrict__ xb, long long n4) {
  long long i = (long long)blockIdx.x * 256 + threadIdx.x;
  if (i >= n4) return;
  float4 v = ((const float4*)x)[i];
  ushort4 o;
  o.x = f2bf(v.x); o.y = f2bf(v.y); o.z = f2bf(v.z); o.w = f2bf(v.w);
  ((ushort4*)xb)[i] = o;
}

// ---------- kernel 2: dequant int4 -> Wt[n][k] bf16 (transposed) ----------
__global__ __launch_bounds__(256) void dequant(
    const int* __restrict__ qw, const int* __restrict__ qz,
    const int* __restrict__ qs, const float* __restrict__ qsz,
    const float* __restrict__ qss, const int* __restrict__ gidx,
    u16* __restrict__ Wt, int IN, int OUT) {
  const int n = blockIdx.x * 64 + (threadIdx.x & 63);
  const int w = threadIdx.x >> 6;            // 0..3
  const int k0 = blockIdx.y * 128 + w * 32;  // one 32-wide group per wave-slice
  const int g = gidx[k0];                    // uniform across wave
  const int kk0 = k0 >> 3;                   // 4 packed rows
  const int zq = ((qz[(size_t)g * (OUT >> 3) + (n >> 3)] >> (4 * (n & 7))) & 15) + 1;
  const float sc = ((float)qs[(size_t)g * OUT + n] - qsz[g]) * qss[g];
  u16* dst = Wt + (size_t)n * IN + k0;
#pragma unroll
  for (int j = 0; j < 4; ++j) {
    const int w32 = qw[(size_t)(kk0 + j) * OUT + n];   // coalesced across lanes
    u16 o[8];
#pragma unroll
    for (int s = 0; s < 8; ++s)
      o[s] = f2bf((float)(((w32 >> (4 * s)) & 15) - zq) * sc);
    uint4 pk;
    pk.x = (u32)o[0] | ((u32)o[1] << 16);
    pk.y = (u32)o[2] | ((u32)o[3] << 16);
    pk.z = (u32)o[4] | ((u32)o[5] << 16);
    pk.w = (u32)o[6] | ((u32)o[7] << 16);
    *(uint4*)(dst + j * 8) = pk;
  }
}

// ---------- kernel 3: 256x256 8-phase bf16 GEMM (m201 template port) ----------
// C = A(MxK)*Bt(NxK)^T.  8 waves (2m x 4n), per-wave 128x64 C.  BK=64,
// buf0 = even K-tiles, buf1 = odd (fixed).  Iter = 2 K-tiles = 8 phases;
// phase = one C-quadrant (2mt x 4nt x 2ksub = 16 MFMA).  B-frags read once
// per tile (phase 0/4: 12 ds_read_b128), A-frags 4 per phase.  One half-tile
// (128 rows, 2 x global_load_lds) staged per phase; counted vmcnt(4) only at
// phases 4 and 8 (never 0 in steady state).
// Stage rotation (iter i computes tiles 2i/buf0, 2i+1/buf1):
//   ph0: buf1.A0<-t2i+1   ph1: buf1.A1<-t2i+1   (dead since prev ph7)
//   ph2: buf0.B0<-t2i+2   ph3: buf0.B1<-t2i+2   (B read only in ph0)
//   ph4: buf0.A0<-t2i+2   ph5: buf0.A1<-t2i+2   (A dead after ph3)
//   ph6: buf1.B0<-t2i+3   ph7: buf1.B1<-t2i+3   (B read only in ph4)
// vmcnt(4) at ph3-end covers buf1 complete before ph4; at ph7-end covers
// buf0 complete before next ph0.  Each wave waits only its own loads; the
// barrier then publishes LDS to all waves (m97 pattern).
// Swizzle: row stride 64 bf16 = 128B = 8 granules; store granule c at
// c^(row&7) (pre-swizzled global source col since gld_lds writes linearly),
// undo on ds_read -> 4 granules/bank-group per 32-lane half = minimum.
#define VM4 asm volatile("s_waitcnt vmcnt(4)" ::: "memory")
#define VM0 asm volatile("s_waitcnt vmcnt(0)" ::: "memory")

__global__ __launch_bounds__(512, 2) void gemm256(const u16* __restrict__ A,
                                                  const u16* __restrict__ Bt,
                                                  float* __restrict__ C,
                                                  int M, int N, int K) {
  __shared__ u16 As[2][16384];
  __shared__ u16 Bs[2][16384];
  const int tid = threadIdx.x;
  const int lane = tid & 63;
  const int wave = tid >> 6;          // 0..7
  const int wm = wave >> 2;           // 0..1
  const int wn = wave & 3;            // 0..3
  const int lr = lane & 15, quad = lane >> 4;

  // bijective XCD-aware block swizzle (m204 form)
  const int nbx = N >> 8;
  const int nwg = gridDim.x;
  const int bid = blockIdx.x;
  const int q8 = nwg >> 3, r8 = nwg & 7;
  const int xcd = bid & 7, loc = bid >> 3;
  const int swz = (xcd < r8 ? xcd * (q8 + 1) : r8 * (q8 + 1) + (xcd - r8) * q8) + loc;
  const int n0 = (swz % nbx) << 8;
  const int m0 = (swz / nbx) << 8;

  floatx4 acc[8][4] = {};

  // ---- staging source (per-thread; carries the store swizzle) ----
  // one call = 64 rows x 64 k: wave w rows w*8+(lane>>3), granule lane&7,
  // source granule ^= row&7
  const int srow = lane >> 3;
  const int sch8 = ((lane & 7) ^ (srow & 7)) * 8;
  const u16* aS = A + (size_t)(m0 + wave * 8 + srow) * K + sch8;
  const u16* bS = Bt + (size_t)(n0 + wave * 8 + srow) * K + sch8;

#define STAGE_A(buf, h, kt) do {                                              \
    const u16* s_ = aS + (size_t)(h) * 128 * K + (size_t)(kt) * 64;           \
    u16* d_ = &As[buf][((h) * 128 + wave * 8) * 64];                          \
    gld16(s_, d_); gld16(s_ + (size_t)64 * K, d_ + 4096);                     \
  } while (0)
#define STAGE_B(buf, h, kt) do {                                              \
    const u16* s_ = bS + (size_t)(h) * 128 * K + (size_t)(kt) * 64;           \
    u16* d_ = &Bs[buf][((h) * 128 + wave * 8) * 64];                          \
    gld16(s_, d_); gld16(s_ + (size_t)64 * K, d_ + 4096);                     \
  } while (0)

  // ---- fragment read bases (swizzle undone; row&7 == lr&7) ----
  const int rl = lr & 7;
  const int cs0 = ((0 * 4 + quad) ^ rl) * 8;   // ksub 0
  const int cs1 = ((1 * 4 + quad) ^ rl) * 8;   // ksub 1
  const u16* a0rd = &As[0][(wm * 128 + lr) * 64];
  const u16* a1rd = &As[1][(wm * 128 + lr) * 64];
  const u16* b0rd = &Bs[0][(wn * 64 + lr) * 64];
  const u16* b1rd = &Bs[1][(wn * 64 + lr) * 64];

  short8 aF[2][2], bF[4][2];

#define PHASE(ARD, BRD, q, LOADB, STG, VMW) do {                              \
    if (LOADB) {                                                              \
      _Pragma("unroll") for (int nt = 0; nt < 4; ++nt) {                      \
        bF[nt][0] = *(const short8*)((BRD) + nt * 1024 + cs0);                \
        bF[nt][1] = *(const short8*)((BRD) + nt * 1024 + cs1);                \
      }                                                                       \
    }                                                                         \
    aF[0][0] = *(const short8*)((ARD) + (2 * (q)) * 1024 + cs0);              \
    aF[0][1] = *(const short8*)((ARD) + (2 * (q)) * 1024 + cs1);              \
    aF[1][0] = *(const short8*)((ARD) + (2 * (q) + 1) * 1024 + cs0);          \
    aF[1][1] = *(const short8*)((ARD) + (2 * (q) + 1) * 1024 + cs1);          \
    STG;                                                                      \
    __builtin_amdgcn_s_barrier();                                             \
    __builtin_amdgcn_s_setprio(1);                                            \
    _Pragma("unroll") for (int s = 0; s < 2; ++s)                             \
      _Pragma("unroll") for (int j = 0; j < 2; ++j)                           \
        _Pragma("unroll") for (int nt = 0; nt < 4; ++nt)                      \
          acc[2 * (q) + j][nt] = __builtin_amdgcn_mfma_f32_16x16x32_bf16(     \
              aF[j][s], bF[nt][s], acc[2 * (q) + j][nt], 0, 0, 0);            \
    __builtin_amdgcn_s_setprio(0);                                            \
    VMW;                                                                      \
    __builtin_amdgcn_s_barrier();                                             \
  } while (0)

  // ---- prologue: buf0 <- tile0 (B,A), buf1.B <- tile1; wait buf0 only ----
  STAGE_B(0, 0, 0); STAGE_B(0, 1, 0);
  STAGE_A(0, 0, 0); STAGE_A(0, 1, 0);
  STAGE_B(1, 0, 1); STAGE_B(1, 1, 1);
  VM4;                                    // oldest 8 = buf0 complete
  __builtin_amdgcn_s_barrier();

  const int NI = K >> 7;                  // iters of 2 K-tiles
  for (int i = 0; i < NI; ++i) {
    const int kt = 2 * i;
    const bool full = (i < NI - 1);
    PHASE(a0rd, b0rd, 0, 1, { STAGE_A(1, 0, kt + 1); }, (void)0);
    PHASE(a0rd, b0rd, 1, 0, { STAGE_A(1, 1, kt + 1); }, (void)0);
    PHASE(a0rd, b0rd, 2, 0, { if (full) STAGE_B(0, 0, kt + 2); }, (void)0);
    PHASE(a0rd, b0rd, 3, 0, { if (full) STAGE_B(0, 1, kt + 2); },
          { if (full) { VM4; } else { VM0; } });
    PHASE(a1rd, b1rd, 0, 1, { if (full) STAGE_A(0, 0, kt + 2); }, (void)0);
    PHASE(a1rd, b1rd, 1, 0, { if (full) STAGE_A(0, 1, kt + 2); }, (void)0);
    PHASE(a1rd, b1rd, 2, 0, { if (full) STAGE_B(1, 0, kt + 3); }, (void)0);
    PHASE(a1rd, b1rd, 3, 0, { if (full) STAGE_B(1, 1, kt + 3); },
          { if (full) { VM4; } });
  }
#undef PHASE
#undef STAGE_A
#undef STAGE_B

  // ---- epilogue: C/D layout col=lane&15, row=quad*4+reg ----
#pragma unroll
  for (int mt = 0; mt < 8; ++mt)
#pragma unroll
    for (int nt = 0; nt < 4; ++nt)
#pragma unroll
      for (int r = 0; r < 4; ++r) {
        int row = m0 + wm * 128 + mt * 16 + quad * 4 + r;
        int col = n0 + wn * 64 + nt * 16 + lr;
        C[(size_t)row * N + col] = acc[mt][nt][r];
      }
}

// ---------- kernel 3b (fallback): 128x128 bf16 GEMM ----------
__global__ __launch_bounds__(256) void gemm(const u16* __restrict__ A,
                                            const u16* __restrict__ Bt,
                                            float* __restrict__ C,
                                            int M, int N, int K) {
  __shared__ u16 As[128 * 64];
  __shared__ u16 Bs[128 * 64];
  const int tid = threadIdx.x;
  const int lane = tid & 63;
  const int wave = tid >> 6;
  const int wm = wave & 1, wn = wave >> 1;
  const int lr = lane & 15, quad = lane >> 4;
  const int m0 = blockIdx.y * 128, n0 = blockIdx.x * 128;

  floatx4 acc[4][4] = {};

  const int srowB = (lane >> 3);
  const int schunk = (lane & 7) ^ srowB;
  const int rowA0 = wave * 32;
  const u16* aSrc = A + (size_t)(m0 + rowA0 + srowB) * K + schunk * 8;
  const u16* bSrc = Bt + (size_t)(n0 + rowA0 + srowB) * K + schunk * 8;
  u16* aDst = &As[rowA0 * 64];
  u16* bDst = &Bs[rowA0 * 64];
  const size_t rstep = (size_t)8 * K;

  const int rx = lr & 7;

  for (int k0 = 0; k0 < K; k0 += 64) {
    __syncthreads();
#pragma unroll
    for (int c = 0; c < 4; ++c) {
      gld16(aSrc + c * rstep + k0, aDst + c * 8 * 64);
      gld16(bSrc + c * rstep + k0, bDst + c * 8 * 64);
    }
    __syncthreads();

#pragma unroll
    for (int h = 0; h < 2; ++h) {
      short8 aF[4], bF[4];
      const int rc = ((quad + 4 * h) ^ rx) * 8;
#pragma unroll
      for (int t = 0; t < 4; ++t) {
        aF[t] = *(const short8*)&As[(wm * 64 + t * 16 + lr) * 64 + rc];
        bF[t] = *(const short8*)&Bs[(wn * 64 + t * 16 + lr) * 64 + rc];
      }
#pragma unroll
      for (int mt = 0; mt < 4; ++mt)
#pragma unroll
        for (int nt = 0; nt < 4; ++nt)
          acc[mt][nt] = __builtin_amdgcn_mfma_f32_16x16x32_bf16(
              aF[mt], bF[nt], acc[mt][nt], 0, 0, 0);
    }
  }

#pragma unroll
  for (int mt = 0; mt < 4; ++mt)
#pragma unroll
    for (int nt = 0; nt < 4; ++nt)
#pragma unroll
      for (int r = 0; r < 4; ++r) {
        int row = m0 + wm * 64 + mt * 16 + quad * 4 + r;
        int col = n0 + wn * 64 + nt * 16 + lr;
        C[(size_t)row * N + col] = acc[mt][nt][r];
      }
}

// ---------- fallback: naive dequant-on-the-fly ----------
__global__ void naive(const float* __restrict__ x, const int* __restrict__ qw,
                      const int* __restrict__ qz, const int* __restrict__ qs,
                      const float* __restrict__ qsz, const float* __restrict__ qss,
                      const int* __restrict__ gidx, float* __restrict__ out,
                      int M, int N, int K) {
  int n = blockIdx.x * 64 + (threadIdx.x & 63);
  int m = blockIdx.y * 4 + (threadIdx.x >> 6);
  if (n >= N || m >= M) return;
  float acc = 0.f;
  for (int kk = 0; kk < K / 8; ++kk) {
    int w32 = qw[(size_t)kk * N + n];
#pragma unroll
    for (int s = 0; s < 8; ++s) {
      int k = kk * 8 + s;
      int g = gidx[k];
      int zq = ((qz[(size_t)g * (N >> 3) + (n >> 3)] >> (4 * (n & 7))) & 15) + 1;
      float sc = ((float)qs[(size_t)g * N + n] - qsz[g]) * qss[g];
      acc += x[(size_t)m * K + k] * ((float)((w32 >> (4 * s)) & 15) - (float)zq) * sc;
    }
  }
  out[(size_t)m * N + n] = acc;
}

extern "C" void kernel_launch(void* const* d_in, const int* in_sizes, int n_in,
                              void* d_out, int out_size, void* d_ws, size_t ws_size,
                              hipStream_t stream) {
  const float* x = (const float*)d_in[0];
  const int* qw = (const int*)d_in[1];
  const int* qz = (const int*)d_in[2];
  const int* qs = (const int*)d_in[3];
  const float* qsz = (const float*)d_in[4];
  const float* qss = (const float*)d_in[5];
  const int* gidx = (const int*)d_in[6];
  const int IN = in_sizes[6];                                   // 4096
  const int OUT = (int)(((long long)in_sizes[1] * 8) / IN);     // 4096
  const int M = in_sizes[0] / IN;                               // 8192
  float* out = (float*)d_out;

  size_t bytesW = (size_t)IN * OUT * 2;
  size_t bytesX = (size_t)M * IN * 2;
  bool haveWs = (ws_size >= bytesW + bytesX);
  bool fast256 = haveWs && (M % 256 == 0) && (OUT % 256 == 0) &&
                 (IN % 128 == 0) && (IN >= 256);
  bool fast128 = haveWs && (M % 128 == 0) && (OUT % 128 == 0) && (IN % 128 == 0);

  if (fast256 || fast128) {
    u16* Wt = (u16*)d_ws;
    u16* Xb = (u16*)((char*)d_ws + bytesW);
    long long n4 = (long long)M * IN / 4;
    int cb = (int)((n4 + 255) / 256);
    xconv<<<cb, 256, 0, stream>>>(x, Xb, n4);
    dequant<<<dim3(OUT / 64, IN / 128), 256, 0, stream>>>(qw, qz, qs, qsz, qss,
                                                          gidx, Wt, IN, OUT);
    if (fast256) {
      int nblk = (M / 256) * (OUT / 256);
      gemm256<<<dim3(nblk), 512, 0, stream>>>(Xb, Wt, out, M, OUT, IN);
    } else {
      gemm<<<dim3(OUT / 128, M / 128), 256, 0, stream>>>(Xb, Wt, out, M, OUT, IN);
    }
  } else {
    naive<<<dim3((OUT + 63) / 64, (M + 3) / 4), 256, 0, stream>>>(
        x, qw, qz, qs, qsz, qss, gidx, out, M, OUT, IN);
  }
}